// Round 2
// baseline (425.388 us; speedup 1.0000x reference)
//
#include <hip/hip_runtime.h>

#define B_ 8
#define C_ 512
#define T_ 8192
#define TOK_ 256
#define CD_ 768
#define H_ 8
#define D_ 64

typedef __attribute__((ext_vector_type(8))) short bf16x8;
typedef __attribute__((ext_vector_type(4))) float f32x4;

__device__ __forceinline__ unsigned short f2bf(float f){
  union { float f; unsigned u; } v; v.f = f;
  return (unsigned short)((v.u + 0x7FFFu + ((v.u >> 16) & 1u)) >> 16);
}

// ---------------- A0: pack Wq into bf16 MFMA B-fragments ----------------
// slot = (kk*32 + ntile)*64 + lane ; element j = Wq[n=ntile*16+(lane&15)][k=kk*32+(lane>>4)*8 + j]
__global__ void pack_wq(const float* __restrict__ Wq, unsigned short* __restrict__ out){
  int slot = blockIdx.x * 256 + threadIdx.x;       // 0..32767
  int ln = slot & 63, nt = (slot >> 6) & 31, kk = slot >> 11;
  int n  = nt * 16 + (ln & 15);
  int k0 = kk * 32 + (ln >> 4) * 8;
  bf16x8 v;
  #pragma unroll
  for (int j = 0; j < 8; j++) v[j] = (short)f2bf(Wq[(size_t)n * C_ + k0 + j]);
  *(bf16x8*)&out[(size_t)slot * 8] = v;
}

// ---------------- A1: context layernorm ----------------
__global__ void ctx_ln(const float* __restrict__ ctx, const float* __restrict__ g,
                       const float* __restrict__ bl, float* __restrict__ outn){
  int row = blockIdx.x;                            // 0..2047  (b*256+n)
  const float* p = ctx + (size_t)row * CD_;
  int tid = threadIdx.x;
  float s1 = 0.f, s2 = 0.f;
  for (int i = tid; i < CD_; i += 256){ float v = p[i]; s1 += v; s2 += v * v; }
  #pragma unroll
  for (int o = 32; o > 0; o >>= 1){ s1 += __shfl_xor(s1, o); s2 += __shfl_xor(s2, o); }
  __shared__ float rs[4][2];
  if ((tid & 63) == 0){ rs[tid >> 6][0] = s1; rs[tid >> 6][1] = s2; }
  __syncthreads();
  s1 = rs[0][0] + rs[1][0] + rs[2][0] + rs[3][0];
  s2 = rs[0][1] + rs[1][1] + rs[2][1] + rs[3][1];
  float m = s1 / (float)CD_;
  float var = s2 / (float)CD_ - m * m;
  float rstd = rsqrtf(var + 1e-5f);
  float* q = outn + (size_t)row * CD_;
  for (int i = tid; i < CD_; i += 256) q[i] = (p[i] - m) * rstd * g[i] + bl[i];
}

// ---------------- A2: K/V projection GEMM (fp32 tiled), bias + mask fused ----------------
// out kv[row][n]: n<512 -> k (masked -> -FLT_MAX), n>=512 -> v (masked -> 0)
__global__ __launch_bounds__(256) void kv_gemm(const float* __restrict__ ctxn,
    const float* __restrict__ Wk, const float* __restrict__ Wv,
    const float* __restrict__ bk, const float* __restrict__ bv,
    const int* __restrict__ mask, float* __restrict__ kv){
  __shared__ float As[32][68];
  __shared__ float Bs[32][68];
  int tid = threadIdx.x;
  int n0 = blockIdx.x * 64;        // 0..960
  int m0 = blockIdx.y * 64;        // 0..1984
  const float* W = (n0 < 512) ? Wk : Wv;
  int nc0 = n0 & 511;
  float acc[4][4] = {};
  int tx = tid & 15, ty = tid >> 4;
  for (int ks = 0; ks < CD_; ks += 32){
    __syncthreads();
    #pragma unroll
    for (int e = 0; e < 8; e++){
      int el = e * 256 + tid;
      int k_l = el & 31, m_l = el >> 5;
      As[k_l][m_l] = ctxn[(size_t)(m0 + m_l) * CD_ + ks + k_l];
      Bs[k_l][m_l] = W[(size_t)(nc0 + m_l) * CD_ + ks + k_l];
    }
    __syncthreads();
    #pragma unroll 4
    for (int k = 0; k < 32; k++){
      float av[4], bv2[4];
      #pragma unroll
      for (int i = 0; i < 4; i++) av[i]  = As[k][ty * 4 + i];
      #pragma unroll
      for (int j = 0; j < 4; j++) bv2[j] = Bs[k][tx * 4 + j];
      #pragma unroll
      for (int i = 0; i < 4; i++)
        #pragma unroll
        for (int j = 0; j < 4; j++)
          acc[i][j] = fmaf(av[i], bv2[j], acc[i][j]);
    }
  }
  #pragma unroll
  for (int i = 0; i < 4; i++){
    int m = m0 + ty * 4 + i;
    int bb = m >> 8, ntok = m & 255;
    bool msk = mask[bb * 256 + ntok] != 0;
    #pragma unroll
    for (int j = 0; j < 4; j++){
      int n = n0 + tx * 4 + j;
      float v = acc[i][j];
      if (n < 512) v = msk ? (v + bk[n]) : -3.402823466e38f;
      else         v = msk ? (v + bv[n - 512]) : 0.0f;
      kv[(size_t)m * 1024 + n] = v;
    }
  }
}

// ---------------- A3: softmax over TOK + attn = k_sm^T @ v, pack to bf16 B-fragments ----------------
__global__ __launch_bounds__(256) void attn_build(const float* __restrict__ kv,
                                                  unsigned short* __restrict__ apk){
  __shared__ float kl[TOK_ * 64];   // k, later softmax weights p
  __shared__ float vl[TOK_ * 64];
  __shared__ float al[64 * 64];     // attn[d][e]
  __shared__ float sc[256];
  __shared__ float mx_l[64], inv_l[64];
  int tid = threadIdx.x;
  int b = blockIdx.x >> 3, h = blockIdx.x & 7;
  for (int e = 0; e < 64; e++){
    int el = e * 256 + tid;
    int n = el >> 6, d = el & 63;
    kl[n * 64 + d] = kv[(size_t)(b * 256 + n) * 1024 + h * 64 + d];
    vl[n * 64 + d] = kv[(size_t)(b * 256 + n) * 1024 + 512 + h * 64 + d];
  }
  __syncthreads();
  int d = tid >> 2, q = tid & 3;
  float mx = -3.402823466e38f;
  for (int j = 0; j < 64; j++) mx = fmaxf(mx, kl[(q * 64 + j) * 64 + d]);
  sc[d * 4 + q] = mx;
  __syncthreads();
  if (tid < 64) mx_l[tid] = fmaxf(fmaxf(sc[tid*4], sc[tid*4+1]), fmaxf(sc[tid*4+2], sc[tid*4+3]));
  __syncthreads();
  float mv = mx_l[d];
  float s = 0.f;
  for (int j = 0; j < 64; j++){
    int n = q * 64 + j;
    float p = expf(kl[n * 64 + d] - mv);
    kl[n * 64 + d] = p;
    s += p;
  }
  sc[d * 4 + q] = s;
  __syncthreads();
  if (tid < 64) inv_l[tid] = 1.0f / (sc[tid*4] + sc[tid*4+1] + sc[tid*4+2] + sc[tid*4+3]);
  __syncthreads();
  float a[16] = {};
  for (int n = 0; n < 256; n++){
    float wv = kl[n * 64 + d];
    #pragma unroll
    for (int j = 0; j < 16; j++) a[j] = fmaf(wv, vl[n * 64 + q * 16 + j], a[j]);
  }
  float inv = inv_l[d];
  #pragma unroll
  for (int j = 0; j < 16; j++) al[d * 64 + q * 16 + j] = a[j] * inv;
  __syncthreads();
  // pack: slot = (kk*4 + nt)*64 + lane ; elem j = attn[d = kk*32+(lane>>4)*8+j][e = nt*16+(lane&15)]
  #pragma unroll
  for (int s2 = 0; s2 < 2; s2++){
    int slot = s2 * 256 + tid;           // 0..511
    int ln = slot & 63, nt = (slot >> 6) & 3, kk = slot >> 8;
    int e = nt * 16 + (ln & 15), d0 = kk * 32 + (ln >> 4) * 8;
    bf16x8 v;
    #pragma unroll
    for (int j = 0; j < 8; j++) v[j] = (short)f2bf(al[(d0 + j) * 64 + e]);
    *(bf16x8*)&apk[((size_t)(b * 8 + h) * 512 + slot) * 8] = v;
  }
}

// ---------------- B: fused LN -> Q-proj (MFMA) -> softmax -> PV (MFMA) -> residual ----------------
__global__ __launch_bounds__(256, 2) void fused_main(const float* __restrict__ x,
    const float* __restrict__ g, const float* __restrict__ bl,
    const unsigned short* __restrict__ wq_pk, const float* __restrict__ bq,
    const unsigned short* __restrict__ attn_pk, float* __restrict__ out){
  __shared__ unsigned short a_lds[32 * 512];   // bf16 A-tile (swizzled); reused for P and fp32 transpose
  __shared__ _Float16 x_l[512 * 32];           // x tile for residual + LN source
  __shared__ float red[32 * 8 * 2];
  __shared__ float m_l[32], rs_l[32];
  const int tid = threadIdx.x;
  const int b = blockIdx.y;
  const int t0 = blockIdx.x * 32;
  const float* xb = x + (size_t)b * C_ * T_ + t0;

  // pass 1: stats + stage x as fp16 (single global read of the tile)
  {
    int t = tid & 31, cg = tid >> 5;
    float s1 = 0.f, s2 = 0.f;
    for (int j = 0; j < 64; j++){
      int c = cg * 64 + j;
      float v = xb[(size_t)c * T_ + t];
      s1 += v; s2 += v * v;
      x_l[c * 32 + t] = (_Float16)v;
    }
    red[(t * 8 + cg) * 2 + 0] = s1;
    red[(t * 8 + cg) * 2 + 1] = s2;
  }
  __syncthreads();
  if (tid < 32){
    float s1 = 0.f, s2 = 0.f;
    for (int j = 0; j < 8; j++){ s1 += red[(tid*8+j)*2]; s2 += red[(tid*8+j)*2+1]; }
    float m = s1 * (1.0f / 512.0f);
    float var = s2 * (1.0f / 512.0f) - m * m;
    m_l[tid] = m;
    rs_l[tid] = rsqrtf(var + 1e-5f);
  }
  __syncthreads();
  // pass 2: LN from x_l (fp16) -> bf16 A tile (XOR-swizzled rows); no global re-read
  {
    int t = tid & 31, cg = tid >> 5;
    float m = m_l[t], rs = rs_l[t];
    for (int o = 0; o < 8; o++){
      int c0 = cg * 64 + o * 8;
      bf16x8 av;
      #pragma unroll
      for (int j = 0; j < 8; j++){
        int c = c0 + j;
        float v = (float)x_l[c * 32 + t];
        av[j] = (short)f2bf((v - m) * rs * g[c] + bl[c]);
      }
      *(bf16x8*)&a_lds[(t * 512 + c0) ^ ((t & 7) << 3)] = av;
    }
  }
  __syncthreads();

  const int w = tid >> 6, ln = tid & 63, lc = ln & 15, lk = ln >> 4;
  // ---- Q GEMM: M=32, per-wave N=128, K=512 ----
  f32x4 acc[2][8];
  #pragma unroll
  for (int i = 0; i < 2; i++)
    #pragma unroll
    for (int j = 0; j < 8; j++) acc[i][j] = (f32x4){0.f, 0.f, 0.f, 0.f};
  const bf16x8* wqv = (const bf16x8*)wq_pk;
  bf16x8 bbuf[2][8];
  #pragma unroll
  for (int nt = 0; nt < 8; nt++) bbuf[0][nt] = wqv[(size_t)(0 * 32 + w * 8 + nt) * 64 + ln];
  #pragma unroll
  for (int kk = 0; kk < 16; kk++){
    int cur = kk & 1, nxt = cur ^ 1;
    if (kk < 15){
      #pragma unroll
      for (int nt = 0; nt < 8; nt++)
        bbuf[nxt][nt] = wqv[(size_t)((kk + 1) * 32 + w * 8 + nt) * 64 + ln];
    }
    bf16x8 af[2];
    #pragma unroll
    for (int mt = 0; mt < 2; mt++){
      int t = mt * 16 + lc;
      af[mt] = *(const bf16x8*)&a_lds[(t * 512 + kk * 32 + lk * 8) ^ ((t & 7) << 3)];
    }
    #pragma unroll
    for (int mt = 0; mt < 2; mt++)
      #pragma unroll
      for (int nt = 0; nt < 8; nt++)
        acc[mt][nt] = __builtin_amdgcn_mfma_f32_16x16x32_bf16(af[mt], bbuf[cur][nt], acc[mt][nt], 0, 0, 0);
  }
  // attn B-fragments for PV (independent of LDS) — issue now
  bf16x8 b2[2][2][4];
  const bf16x8* apk = (const bf16x8*)attn_pk;
  #pragma unroll
  for (int hh = 0; hh < 2; hh++)
    #pragma unroll
    for (int k2 = 0; k2 < 2; k2++)
      #pragma unroll
      for (int np = 0; np < 4; np++)
        b2[hh][k2][np] = apk[((size_t)(b * 8 + (2 * w + hh)) * 512 + (k2 * 4 + np) * 64 + ln)];
  // bias + per-head softmax (over D=64: 4 regs x 16 lanes)
  float bqv[8];
  #pragma unroll
  for (int nt = 0; nt < 8; nt++) bqv[nt] = bq[w * 128 + nt * 16 + lc];
  #pragma unroll
  for (int mt = 0; mt < 2; mt++)
    #pragma unroll
    for (int r = 0; r < 4; r++)
      #pragma unroll
      for (int h2 = 0; h2 < 2; h2++){
        float v[4];
        #pragma unroll
        for (int j = 0; j < 4; j++) v[j] = acc[mt][h2 * 4 + j][r] + bqv[h2 * 4 + j];
        float mx = fmaxf(fmaxf(v[0], v[1]), fmaxf(v[2], v[3]));
        #pragma unroll
        for (int o = 1; o < 16; o <<= 1) mx = fmaxf(mx, __shfl_xor(mx, o));
        float e[4], s = 0.f;
        #pragma unroll
        for (int j = 0; j < 4; j++){ e[j] = expf(v[j] - mx); s += e[j]; }
        #pragma unroll
        for (int o = 1; o < 16; o <<= 1) s += __shfl_xor(s, o);
        float inv = 1.0f / s;
        #pragma unroll
        for (int j = 0; j < 4; j++) acc[mt][h2 * 4 + j][r] = e[j] * inv;
      }
  __syncthreads();                 // everyone done reading A-tile
  // store P (bf16) into a_lds (same swizzle)
  #pragma unroll
  for (int mt = 0; mt < 2; mt++)
    #pragma unroll
    for (int r = 0; r < 4; r++){
      int t = mt * 16 + lk * 4 + r;
      #pragma unroll
      for (int nt = 0; nt < 8; nt++){
        int col = w * 128 + nt * 16 + lc;
        a_lds[(t * 512 + col) ^ ((t & 7) << 3)] = f2bf(acc[mt][nt][r]);
      }
    }
  __syncthreads();
  // ---- PV: per wave 2 heads, out = P(32x64) @ attn(64x64) per head ----
  f32x4 acc2[2][2][4];
  #pragma unroll
  for (int i = 0; i < 2; i++)
    #pragma unroll
    for (int j = 0; j < 2; j++)
      #pragma unroll
      for (int k = 0; k < 4; k++) acc2[i][j][k] = (f32x4){0.f, 0.f, 0.f, 0.f};
  #pragma unroll
  for (int k2 = 0; k2 < 2; k2++){
    bf16x8 a2[2][2];
    #pragma unroll
    for (int mt = 0; mt < 2; mt++)
      #pragma unroll
      for (int hh = 0; hh < 2; hh++){
        int t = mt * 16 + lc;
        int col = w * 128 + hh * 64 + k2 * 32 + lk * 8;
        a2[mt][hh] = *(const bf16x8*)&a_lds[(t * 512 + col) ^ ((t & 7) << 3)];
      }
    #pragma unroll
    for (int mt = 0; mt < 2; mt++)
      #pragma unroll
      for (int hh = 0; hh < 2; hh++)
        #pragma unroll
        for (int np = 0; np < 4; np++)
          acc2[mt][hh][np] = __builtin_amdgcn_mfma_f32_16x16x32_bf16(a2[mt][hh], b2[hh][k2][np], acc2[mt][hh][np], 0, 0, 0);
  }
  // ---- epilogue: transpose via LDS (wave-private band), residual, coalesced store ----
  float* trf = (float*)a_lds;
  const int tt = ln & 31, jj = ln >> 5;
  for (int gq = 0; gq < 8; gq++){
    int hh = gq >> 2, np = gq & 3;
    __syncthreads();
    #pragma unroll
    for (int mt = 0; mt < 2; mt++)
      #pragma unroll
      for (int r = 0; r < 4; r++){
        int t = mt * 16 + lk * 4 + r;
        trf[(t * 256 + w * 64 + lc) ^ ((t & 7) << 2)] = acc2[mt][hh][np][r];
      }
    __syncthreads();
    #pragma unroll
    for (int c8 = 0; c8 < 8; c8++){
      int cl = jj * 8 + c8;
      float o = trf[(tt * 256 + w * 64 + cl) ^ ((tt & 7) << 2)];
      int c = w * 128 + hh * 64 + np * 16 + cl;
      float xv = (float)x_l[c * 32 + tt];
      out[((size_t)b * C_ + c) * T_ + t0 + tt] = xv + o;
    }
  }
}

extern "C" void kernel_launch(void* const* d_in, const int* in_sizes, int n_in,
                              void* d_out, int out_size, void* d_ws, size_t ws_size,
                              hipStream_t stream) {
  (void)in_sizes; (void)n_in; (void)out_size; (void)ws_size;
  const float* x     = (const float*)d_in[0];
  const float* ctx   = (const float*)d_in[1];
  const int*   mask  = (const int*)d_in[2];
  const float* ln_g  = (const float*)d_in[3];
  const float* ln_b  = (const float*)d_in[4];
  const float* cln_g = (const float*)d_in[5];
  const float* cln_b = (const float*)d_in[6];
  const float* Wq    = (const float*)d_in[7];
  const float* bq    = (const float*)d_in[8];
  const float* Wk    = (const float*)d_in[9];
  const float* bk    = (const float*)d_in[10];
  const float* Wv    = (const float*)d_in[11];
  const float* bv    = (const float*)d_in[12];
  float* out = (float*)d_out;
  char* wsb = (char*)d_ws;
  float* ctx_n = (float*)wsb;                                   // 6,291,456 B
  float* kv    = (float*)(wsb + 6291456);                       // 8,388,608 B
  unsigned short* wq_pk   = (unsigned short*)(wsb + 14680064);  //   524,288 B
  unsigned short* attn_pk = (unsigned short*)(wsb + 15204352);  //   524,288 B

  pack_wq<<<128, 256, 0, stream>>>(Wq, wq_pk);
  ctx_ln<<<2048, 256, 0, stream>>>(ctx, cln_g, cln_b, ctx_n);
  kv_gemm<<<dim3(16, 32), 256, 0, stream>>>(ctx_n, Wk, Wv, bk, bv, mask, kv);
  attn_build<<<64, 256, 0, stream>>>(kv, attn_pk);
  fused_main<<<dim3(T_ / 32, B_), 256, 0, stream>>>(x, ln_g, ln_b, wq_pk, bq, attn_pk, out);
}

// Round 5
// 369.245 us; speedup vs baseline: 1.1520x; 1.1520x over previous
//
#include <hip/hip_runtime.h>

#define B_ 8
#define C_ 512
#define T_ 8192
#define TOK_ 256
#define CD_ 768

typedef __attribute__((ext_vector_type(8))) short bf16x8;
typedef __attribute__((ext_vector_type(4))) float f32x4;

__device__ __forceinline__ unsigned short f2bf(float f){
  union { float f; unsigned u; } v; v.f = f;
  return (unsigned short)((v.u + 0x7FFFu + ((v.u >> 16) & 1u)) >> 16);
}

// ---------------- A0: pack Wq into bf16 MFMA B-fragments ----------------
__global__ void pack_wq(const float* __restrict__ Wq, unsigned short* __restrict__ out){
  int slot = blockIdx.x * 256 + threadIdx.x;       // 0..32767
  int ln = slot & 63, nt = (slot >> 6) & 31, kk = slot >> 11;
  int n  = nt * 16 + (ln & 15);
  int k0 = kk * 32 + (ln >> 4) * 8;
  bf16x8 v;
  #pragma unroll
  for (int j = 0; j < 8; j++) v[j] = (short)f2bf(Wq[(size_t)n * C_ + k0 + j]);
  *(bf16x8*)&out[(size_t)slot * 8] = v;
}

// ---------------- A0b: pack Wk|Wv head-sliced bf16 B-fragments ----------------
// slot = ((h*24 + kk)*8 + nt)*64 + ln ; nt<4 -> Wk col-tile, nt>=4 -> Wv
__global__ void pack_wkv(const float* __restrict__ Wk, const float* __restrict__ Wv,
                         unsigned short* __restrict__ out){
  int slot = blockIdx.x * 256 + threadIdx.x;       // 0..98303
  int ln = slot & 63, nt = (slot >> 6) & 7;
  int kkh = slot >> 9;
  int kk = kkh % 24, h = kkh / 24;
  const float* W = (nt < 4) ? Wk : Wv;
  int row = h * 64 + (nt & 3) * 16 + (ln & 15);
  int k0 = kk * 32 + (ln >> 4) * 8;
  bf16x8 v;
  #pragma unroll
  for (int j = 0; j < 8; j++) v[j] = (short)f2bf(W[(size_t)row * CD_ + k0 + j]);
  *(bf16x8*)&out[(size_t)slot * 8] = v;
}

// ---------------- A1: context layernorm -> bf16 rows ----------------
__global__ void ctx_ln(const float* __restrict__ ctx, const float* __restrict__ g,
                       const float* __restrict__ bl, unsigned short* __restrict__ outn){
  int row = blockIdx.x;                            // 0..2047
  const float* p = ctx + (size_t)row * CD_;
  int tid = threadIdx.x;
  float s1 = 0.f, s2 = 0.f;
  for (int i = tid; i < CD_; i += 256){ float v = p[i]; s1 += v; s2 += v * v; }
  #pragma unroll
  for (int o = 32; o > 0; o >>= 1){ s1 += __shfl_xor(s1, o); s2 += __shfl_xor(s2, o); }
  __shared__ float rs[4][2];
  if ((tid & 63) == 0){ rs[tid >> 6][0] = s1; rs[tid >> 6][1] = s2; }
  __syncthreads();
  s1 = rs[0][0] + rs[1][0] + rs[2][0] + rs[3][0];
  s2 = rs[0][1] + rs[1][1] + rs[2][1] + rs[3][1];
  float m = s1 / (float)CD_;
  float var = s2 / (float)CD_ - m * m;
  float rstd = rsqrtf(var + 1e-5f);
  unsigned short* q = outn + (size_t)row * CD_;
  for (int i = tid; i < CD_; i += 256) q[i] = f2bf((p[i] - m) * rstd * g[i] + bl[i]);
}

// ---------------- A2: fused context pipeline: KV-proj (MFMA) + mask + softmax + attn (MFMA) ----------------
// one block per (b,h); 256 threads = 4 waves; wave w owns ctx rows [64w,64w+64)
__global__ __launch_bounds__(256) void ctx_attn(const unsigned short* __restrict__ ctx_nb,
    const unsigned short* __restrict__ wkv_pk,
    const float* __restrict__ bk, const float* __restrict__ bv,
    const int* __restrict__ mask, unsigned short* __restrict__ apk){
  __shared__ __align__(16) char smem[75776];
  unsigned short* a_st  = (unsigned short*)smem;            // [2][8192] staging (aliases p_lds)
  unsigned short* p_lds = (unsigned short*)smem;            // [64][256] bf16, d-major
  unsigned short* v_lds = (unsigned short*)(smem + 32768);  // [64][256] bf16, e-major
  unsigned short* al    = (unsigned short*)(smem + 65536);  // [64][64] attn bf16
  float* wred = (float*)(smem + 73728);                     // [4][64]
  int* msk_l  = (int*)(smem + 74752);                       // [256]

  const int tid = threadIdx.x;
  const int b = blockIdx.x >> 3, h = blockIdx.x & 7;
  msk_l[tid] = mask[b * 256 + tid];

  const unsigned short* cb = ctx_nb + (size_t)b * 256 * CD_;
  const int w = tid >> 6, ln = tid & 63, lc = ln & 15, lk = ln >> 4;

  // stage kk=0 (row = tid, 32 k-values = 4 x bf16x8)
  {
    const bf16x8* src = (const bf16x8*)(cb + (size_t)tid * CD_);
    #pragma unroll
    for (int s = 0; s < 4; s++){
      bf16x8 vv = src[s];
      *(bf16x8*)&a_st[(tid * 32 + s * 8) ^ ((tid & 7) << 3)] = vv;
    }
  }
  const bf16x8* wv_ = (const bf16x8*)wkv_pk;
  const size_t wbase = (size_t)h * 24 * 8 * 64;
  f32x4 acc[4][8];
  #pragma unroll
  for (int i = 0; i < 4; i++)
    #pragma unroll
    for (int j = 0; j < 8; j++) acc[i][j] = (f32x4){0.f,0.f,0.f,0.f};
  bf16x8 bbuf[2][8];
  #pragma unroll
  for (int nt = 0; nt < 8; nt++) bbuf[0][nt] = wv_[wbase + (size_t)(0 * 8 + nt) * 64 + ln];
  __syncthreads();

  // GEMM: M=256 (n), N=128 (64 k-d | 64 v-e), K=768
  for (int kk = 0; kk < 24; kk++){
    int cur = kk & 1;
    if (kk < 23){
      const bf16x8* src = (const bf16x8*)(cb + (size_t)tid * CD_ + (kk + 1) * 32);
      unsigned short* dst = a_st + (cur ^ 1) * 8192;
      #pragma unroll
      for (int s = 0; s < 4; s++){
        bf16x8 vv = src[s];
        *(bf16x8*)&dst[(tid * 32 + s * 8) ^ ((tid & 7) << 3)] = vv;
      }
      #pragma unroll
      for (int nt = 0; nt < 8; nt++)
        bbuf[cur ^ 1][nt] = wv_[wbase + (size_t)((kk + 1) * 8 + nt) * 64 + ln];
    }
    bf16x8 af[4];
    #pragma unroll
    for (int mt = 0; mt < 4; mt++){
      int row = w * 64 + mt * 16 + lc;
      af[mt] = *(const bf16x8*)&a_st[cur * 8192 + ((row * 32 + lk * 8) ^ ((row & 7) << 3))];
    }
    #pragma unroll
    for (int mt = 0; mt < 4; mt++)
      #pragma unroll
      for (int nt = 0; nt < 8; nt++)
        acc[mt][nt] = __builtin_amdgcn_mfma_f32_16x16x32_bf16(af[mt], bbuf[cur][nt], acc[mt][nt], 0, 0, 0);
    __syncthreads();
  }

  // bias + mask
  float bia[8];
  #pragma unroll
  for (int nt = 0; nt < 8; nt++)
    bia[nt] = (nt < 4) ? bk[h * 64 + nt * 16 + lc] : bv[h * 64 + (nt - 4) * 16 + lc];
  bool mk[4][4];
  #pragma unroll
  for (int mt = 0; mt < 4; mt++)
    #pragma unroll
    for (int r = 0; r < 4; r++)
      mk[mt][r] = msk_l[w * 64 + mt * 16 + lk * 4 + r] != 0;

  // softmax over n for k-part (nt 0..3): column d = nt*16+lc
  float cred[4];
  #pragma unroll
  for (int nt = 0; nt < 4; nt++){
    float mx = -3.402823466e38f;
    #pragma unroll
    for (int mt = 0; mt < 4; mt++)
      #pragma unroll
      for (int r = 0; r < 4; r++)
        if (mk[mt][r]) mx = fmaxf(mx, acc[mt][nt][r] + bia[nt]);
    mx = fmaxf(mx, __shfl_xor(mx, 16));
    mx = fmaxf(mx, __shfl_xor(mx, 32));
    cred[nt] = mx;
  }
  if (lk == 0){
    #pragma unroll
    for (int nt = 0; nt < 4; nt++) wred[w * 64 + nt * 16 + lc] = cred[nt];
  }
  __syncthreads();
  float gmx[4];
  #pragma unroll
  for (int nt = 0; nt < 4; nt++){
    int d = nt * 16 + lc;
    gmx[nt] = fmaxf(fmaxf(wred[d], wred[64 + d]), fmaxf(wred[128 + d], wred[192 + d]));
  }
  __syncthreads();
  #pragma unroll
  for (int nt = 0; nt < 4; nt++){
    float s = 0.f;
    #pragma unroll
    for (int mt = 0; mt < 4; mt++)
      #pragma unroll
      for (int r = 0; r < 4; r++){
        float p = mk[mt][r] ? expf(acc[mt][nt][r] + bia[nt] - gmx[nt]) : 0.f;
        acc[mt][nt][r] = p;
        s += p;
      }
    s += __shfl_xor(s, 16);
    s += __shfl_xor(s, 32);
    cred[nt] = s;
  }
  if (lk == 0){
    #pragma unroll
    for (int nt = 0; nt < 4; nt++) wred[w * 64 + nt * 16 + lc] = cred[nt];
  }
  __syncthreads();
  float ginv[4];
  #pragma unroll
  for (int nt = 0; nt < 4; nt++){
    int d = nt * 16 + lc;
    float s = wred[d] + wred[64 + d] + wred[128 + d] + wred[192 + d];
    ginv[nt] = 1.0f / fmaxf(s, 1e-30f);
  }
  // write p_lds[d][n], v_lds[e][n] (bf16, row-swizzled) — safe: all GEMM reads done
  #pragma unroll
  for (int nt = 0; nt < 4; nt++){
    int d = nt * 16 + lc;
    #pragma unroll
    for (int mt = 0; mt < 4; mt++)
      #pragma unroll
      for (int r = 0; r < 4; r++){
        int n = w * 64 + mt * 16 + lk * 4 + r;
        p_lds[(d * 256 + n) ^ ((d & 7) << 3)] = f2bf(acc[mt][nt][r] * ginv[nt]);
      }
  }
  #pragma unroll
  for (int nt = 4; nt < 8; nt++){
    int e = (nt - 4) * 16 + lc;
    #pragma unroll
    for (int mt = 0; mt < 4; mt++)
      #pragma unroll
      for (int r = 0; r < 4; r++){
        int n = w * 64 + mt * 16 + lk * 4 + r;
        float vv = mk[mt][r] ? (acc[mt][nt][r] + bia[nt]) : 0.f;
        v_lds[(e * 256 + n) ^ ((e & 7) << 3)] = f2bf(vv);
      }
  }
  __syncthreads();

  // attn = p^T @ v : M=64(d) N=64(e) K=256(n); wave w does d-rows [16w,16w+16)
  f32x4 acc2[4];
  #pragma unroll
  for (int i = 0; i < 4; i++) acc2[i] = (f32x4){0.f,0.f,0.f,0.f};
  #pragma unroll
  for (int kk = 0; kk < 8; kk++){
    int d = w * 16 + lc;
    bf16x8 pa = *(const bf16x8*)&p_lds[(d * 256 + kk * 32 + lk * 8) ^ ((d & 7) << 3)];
    #pragma unroll
    for (int nt2 = 0; nt2 < 4; nt2++){
      int e = nt2 * 16 + lc;
      bf16x8 vb = *(const bf16x8*)&v_lds[(e * 256 + kk * 32 + lk * 8) ^ ((e & 7) << 3)];
      acc2[nt2] = __builtin_amdgcn_mfma_f32_16x16x32_bf16(pa, vb, acc2[nt2], 0, 0, 0);
    }
  }
  #pragma unroll
  for (int nt2 = 0; nt2 < 4; nt2++)
    #pragma unroll
    for (int r = 0; r < 4; r++)
      al[(w * 16 + lk * 4 + r) * 64 + nt2 * 16 + lc] = f2bf(acc2[nt2][r]);
  __syncthreads();

  // pack apk (layout identical to previous working version)
  #pragma unroll
  for (int s2 = 0; s2 < 2; s2++){
    int slot = s2 * 256 + tid;           // 0..511
    int l2 = slot & 63, nt = (slot >> 6) & 3, kk = slot >> 8;
    int e = nt * 16 + (l2 & 15), d0 = kk * 32 + (l2 >> 4) * 8;
    bf16x8 v;
    #pragma unroll
    for (int j = 0; j < 8; j++) v[j] = (short)al[(d0 + j) * 64 + e];
    *(bf16x8*)&apk[((size_t)(b * 8 + h) * 512 + slot) * 8] = v;
  }
}

// ---------------- B: fused LN -> Q-proj (MFMA) -> softmax -> PV (MFMA) -> residual ----------------
__global__ __launch_bounds__(256, 3) void fused_main(const float* __restrict__ x,
    const float* __restrict__ g, const float* __restrict__ bl,
    const unsigned short* __restrict__ wq_pk, const float* __restrict__ bq,
    const unsigned short* __restrict__ attn_pk, float* __restrict__ out){
  __shared__ unsigned short a_lds[32 * 512];   // bf16 A-tile (swizzled); reused for P and fp32 transpose
  __shared__ float red[32 * 8 * 2];
  __shared__ float m_l[32], rs_l[32];
  const int tid = threadIdx.x;
  const int b = blockIdx.y;
  const int t0 = blockIdx.x * 32;
  const float* xb = x + (size_t)b * C_ * T_ + t0;

  // pass 1: stats only
  {
    int t = tid & 31, cg = tid >> 5;
    float s1 = 0.f, s2 = 0.f;
    for (int j = 0; j < 64; j++){
      int c = cg * 64 + j;
      float v = xb[(size_t)c * T_ + t];
      s1 += v; s2 += v * v;
    }
    red[(t * 8 + cg) * 2 + 0] = s1;
    red[(t * 8 + cg) * 2 + 1] = s2;
  }
  __syncthreads();
  if (tid < 32){
    float s1 = 0.f, s2 = 0.f;
    #pragma unroll
    for (int j = 0; j < 8; j++){ s1 += red[(tid*8+j)*2]; s2 += red[(tid*8+j)*2+1]; }
    float m = s1 * (1.0f / 512.0f);
    float var = s2 * (1.0f / 512.0f) - m * m;
    m_l[tid] = m;
    rs_l[tid] = rsqrtf(var + 1e-5f);
  }
  __syncthreads();
  // pass 2: LN from L2-warm re-read -> bf16 A tile (XOR-swizzled rows)
  {
    int t = tid & 31, cg = tid >> 5;
    float m = m_l[t], rs = rs_l[t];
    for (int o = 0; o < 8; o++){
      int c0 = cg * 64 + o * 8;
      bf16x8 av;
      #pragma unroll
      for (int j = 0; j < 8; j++){
        int c = c0 + j;
        float v = xb[(size_t)c * T_ + t];
        av[j] = (short)f2bf((v - m) * rs * g[c] + bl[c]);
      }
      *(bf16x8*)&a_lds[(t * 512 + c0) ^ ((t & 7) << 3)] = av;
    }
  }
  __syncthreads();

  const int w = tid >> 6, ln = tid & 63, lc = ln & 15, lk = ln >> 4;
  // ---- Q GEMM: M=32, per-wave N=128, K=512 ----
  f32x4 acc[2][8];
  #pragma unroll
  for (int i = 0; i < 2; i++)
    #pragma unroll
    for (int j = 0; j < 8; j++) acc[i][j] = (f32x4){0.f, 0.f, 0.f, 0.f};
  const bf16x8* wqv = (const bf16x8*)wq_pk;
  bf16x8 bbuf[2][8];
  #pragma unroll
  for (int nt = 0; nt < 8; nt++) bbuf[0][nt] = wqv[(size_t)(w * 8 + nt) * 64 + ln];
  #pragma unroll
  for (int kk = 0; kk < 16; kk++){
    int cur = kk & 1, nxt = cur ^ 1;
    if (kk < 15){
      #pragma unroll
      for (int nt = 0; nt < 8; nt++)
        bbuf[nxt][nt] = wqv[(size_t)((kk + 1) * 32 + w * 8 + nt) * 64 + ln];
    }
    bf16x8 af[2];
    #pragma unroll
    for (int mt = 0; mt < 2; mt++){
      int t = mt * 16 + lc;
      af[mt] = *(const bf16x8*)&a_lds[(t * 512 + kk * 32 + lk * 8) ^ ((t & 7) << 3)];
    }
    #pragma unroll
    for (int mt = 0; mt < 2; mt++)
      #pragma unroll
      for (int nt = 0; nt < 8; nt++)
        acc[mt][nt] = __builtin_amdgcn_mfma_f32_16x16x32_bf16(af[mt], bbuf[cur][nt], acc[mt][nt], 0, 0, 0);
  }
  // attn B-fragments for PV
  bf16x8 b2[2][2][4];
  const bf16x8* apk = (const bf16x8*)attn_pk;
  #pragma unroll
  for (int hh = 0; hh < 2; hh++)
    #pragma unroll
    for (int k2 = 0; k2 < 2; k2++)
      #pragma unroll
      for (int np = 0; np < 4; np++)
        b2[hh][k2][np] = apk[((size_t)(b * 8 + (2 * w + hh)) * 512 + (k2 * 4 + np) * 64 + ln)];
  // bias + per-head softmax over D=64
  float bqv[8];
  #pragma unroll
  for (int nt = 0; nt < 8; nt++) bqv[nt] = bq[w * 128 + nt * 16 + lc];
  #pragma unroll
  for (int mt = 0; mt < 2; mt++)
    #pragma unroll
    for (int r = 0; r < 4; r++)
      #pragma unroll
      for (int h2 = 0; h2 < 2; h2++){
        float v[4];
        #pragma unroll
        for (int j = 0; j < 4; j++) v[j] = acc[mt][h2 * 4 + j][r] + bqv[h2 * 4 + j];
        float mx = fmaxf(fmaxf(v[0], v[1]), fmaxf(v[2], v[3]));
        #pragma unroll
        for (int o = 1; o < 16; o <<= 1) mx = fmaxf(mx, __shfl_xor(mx, o));
        float e[4], s = 0.f;
        #pragma unroll
        for (int j = 0; j < 4; j++){ e[j] = expf(v[j] - mx); s += e[j]; }
        #pragma unroll
        for (int o = 1; o < 16; o <<= 1) s += __shfl_xor(s, o);
        float inv = 1.0f / s;
        #pragma unroll
        for (int j = 0; j < 4; j++) acc[mt][h2 * 4 + j][r] = e[j] * inv;
      }
  __syncthreads();                 // A-tile reads complete
  // store P (bf16) into a_lds (same swizzle)
  #pragma unroll
  for (int mt = 0; mt < 2; mt++)
    #pragma unroll
    for (int r = 0; r < 4; r++){
      int t = mt * 16 + lk * 4 + r;
      #pragma unroll
      for (int nt = 0; nt < 8; nt++){
        int col = w * 128 + nt * 16 + lc;
        a_lds[(t * 512 + col) ^ ((t & 7) << 3)] = f2bf(acc[mt][nt][r]);
      }
    }
  __syncthreads();
  // ---- PV: per wave 2 heads ----
  f32x4 acc2[2][2][4];
  #pragma unroll
  for (int i = 0; i < 2; i++)
    #pragma unroll
    for (int j = 0; j < 2; j++)
      #pragma unroll
      for (int k = 0; k < 4; k++) acc2[i][j][k] = (f32x4){0.f, 0.f, 0.f, 0.f};
  #pragma unroll
  for (int k2 = 0; k2 < 2; k2++){
    bf16x8 a2[2][2];
    #pragma unroll
    for (int mt = 0; mt < 2; mt++)
      #pragma unroll
      for (int hh = 0; hh < 2; hh++){
        int t = mt * 16 + lc;
        int col = w * 128 + hh * 64 + k2 * 32 + lk * 8;
        a2[mt][hh] = *(const bf16x8*)&a_lds[(t * 512 + col) ^ ((t & 7) << 3)];
      }
    #pragma unroll
    for (int mt = 0; mt < 2; mt++)
      #pragma unroll
      for (int hh = 0; hh < 2; hh++)
        #pragma unroll
        for (int np = 0; np < 4; np++)
          acc2[mt][hh][np] = __builtin_amdgcn_mfma_f32_16x16x32_bf16(a2[mt][hh], b2[hh][k2][np], acc2[mt][hh][np], 0, 0, 0);
  }
  // ---- epilogue: 2 rounds (hh), conflict-free bijective swizzle, residual from L2 ----
  float* trf = (float*)a_lds;                    // 32 x 256 f32 = 32 KB
  const int tt = ln & 31;
  const int rowid = (w << 1) | (ln >> 5);        // 0..7
  #pragma unroll
  for (int hh = 0; hh < 2; hh++){
    __syncthreads();
    #pragma unroll
    for (int np = 0; np < 4; np++)
      #pragma unroll
      for (int mt = 0; mt < 2; mt++)
        #pragma unroll
        for (int r = 0; r < 4; r++){
          int t = mt * 16 + lk * 4 + r;
          int cc = w * 64 + np * 16 + lc;
          trf[(t * 256 + cc) ^ (((t & 7) << 2) | ((t >> 3) & 3))] = acc2[mt][hh][np][r];
        }
    __syncthreads();
    #pragma unroll
    for (int i = 0; i < 32; i++){
      int cc = i * 8 + rowid;                    // 0..255
      int c = (cc >> 6) * 128 + hh * 64 + (cc & 63);
      float o = trf[(tt * 256 + cc) ^ (((tt & 7) << 2) | ((tt >> 3) & 3))];
      float xv = xb[(size_t)c * T_ + tt];
      out[((size_t)b * C_ + c) * T_ + t0 + tt] = xv + o;
    }
  }
}

extern "C" void kernel_launch(void* const* d_in, const int* in_sizes, int n_in,
                              void* d_out, int out_size, void* d_ws, size_t ws_size,
                              hipStream_t stream) {
  (void)in_sizes; (void)n_in; (void)out_size; (void)ws_size;
  const float* x     = (const float*)d_in[0];
  const float* ctx   = (const float*)d_in[1];
  const int*   mask  = (const int*)d_in[2];
  const float* ln_g  = (const float*)d_in[3];
  const float* ln_b  = (const float*)d_in[4];
  const float* cln_g = (const float*)d_in[5];
  const float* cln_b = (const float*)d_in[6];
  const float* Wq    = (const float*)d_in[7];
  const float* bq    = (const float*)d_in[8];
  const float* Wk    = (const float*)d_in[9];
  const float* bk    = (const float*)d_in[10];
  const float* Wv    = (const float*)d_in[11];
  const float* bv    = (const float*)d_in[12];
  float* out = (float*)d_out;
  char* wsb = (char*)d_ws;
  unsigned short* ctx_nb = (unsigned short*)wsb;                // 3,145,728 B
  unsigned short* wq_pk  = (unsigned short*)(wsb + 3145728);    //   524,288 B
  unsigned short* wkv_pk = (unsigned short*)(wsb + 3670016);    // 1,572,864 B
  unsigned short* apk    = (unsigned short*)(wsb + 5242880);    //   524,288 B

  pack_wq<<<128, 256, 0, stream>>>(Wq, wq_pk);
  pack_wkv<<<384, 256, 0, stream>>>(Wk, Wv, wkv_pk);
  ctx_ln<<<2048, 256, 0, stream>>>(ctx, cln_g, cln_b, ctx_nb);
  ctx_attn<<<64, 256, 0, stream>>>(ctx_nb, wkv_pk, bk, bv, mask, apk);
  fused_main<<<dim3(T_ / 32, B_), 256, 0, stream>>>(x, ln_g, ln_b, wq_pk, bq, apk, out);
}

// Round 8
// 356.453 us; speedup vs baseline: 1.1934x; 1.0359x over previous
//
#include <hip/hip_runtime.h>

#define B_ 8
#define C_ 512
#define T_ 8192
#define TOK_ 256
#define CD_ 768

typedef __attribute__((ext_vector_type(8))) short bf16x8;
typedef __attribute__((ext_vector_type(4))) float f32x4;

__device__ __forceinline__ unsigned short f2bf(float f){
  union { float f; unsigned u; } v; v.f = f;
  return (unsigned short)((v.u + 0x7FFFu + ((v.u >> 16) & 1u)) >> 16);
}
__device__ __forceinline__ float bf2f(unsigned short h){
  union { unsigned u; float f; } v; v.u = ((unsigned)h) << 16;
  return v.f;
}

// ---------------- A: merged prep: ctx layernorm + Wq pack + Wk/Wv pack ----------------
__global__ __launch_bounds__(256) void prep(const float* __restrict__ ctx,
    const float* __restrict__ cg_, const float* __restrict__ cb_,
    const float* __restrict__ Wq, const float* __restrict__ Wk, const float* __restrict__ Wv,
    unsigned short* __restrict__ ctx_nb, unsigned short* __restrict__ wq_pk,
    unsigned short* __restrict__ wkv_pk){
  __shared__ float rs[4][2];
  const int bid = blockIdx.x;
  const int tid = threadIdx.x;
  if (bid < 2048){
    // ---- ctx_ln row ----
    const float* p = ctx + (size_t)bid * CD_;
    float s1 = 0.f, s2 = 0.f;
    for (int i = tid; i < CD_; i += 256){ float v = p[i]; s1 += v; s2 += v * v; }
    #pragma unroll
    for (int o = 32; o > 0; o >>= 1){ s1 += __shfl_xor(s1, o); s2 += __shfl_xor(s2, o); }
    if ((tid & 63) == 0){ rs[tid >> 6][0] = s1; rs[tid >> 6][1] = s2; }
    __syncthreads();
    s1 = rs[0][0] + rs[1][0] + rs[2][0] + rs[3][0];
    s2 = rs[0][1] + rs[1][1] + rs[2][1] + rs[3][1];
    float m = s1 / (float)CD_;
    float var = s2 / (float)CD_ - m * m;
    float rstd = rsqrtf(var + 1e-5f);
    unsigned short* q = ctx_nb + (size_t)bid * CD_;
    for (int i = tid; i < CD_; i += 256) q[i] = f2bf((p[i] - m) * rstd * cg_[i] + cb_[i]);
  } else if (bid < 2176){
    // ---- pack Wq: slot=(kk*32+nt)*64+ln ; elem j = Wq[nt*16+(ln&15)][kk*32+(ln>>4)*8+j]
    int slot = (bid - 2048) * 256 + tid;             // 0..32767
    int ln = slot & 63, nt = (slot >> 6) & 31, kk = slot >> 11;
    int n  = nt * 16 + (ln & 15);
    int k0 = kk * 32 + (ln >> 4) * 8;
    bf16x8 v;
    #pragma unroll
    for (int j = 0; j < 8; j++) v[j] = (short)f2bf(Wq[(size_t)n * C_ + k0 + j]);
    *(bf16x8*)&wq_pk[(size_t)slot * 8] = v;
  } else {
    // ---- pack Wk|Wv: slot=((h*24+kk)*8+nt)*64+ln ; nt<4 -> Wk, nt>=4 -> Wv
    int slot = (bid - 2176) * 256 + tid;             // 0..98303
    int ln = slot & 63, nt = (slot >> 6) & 7;
    int kkh = slot >> 9;
    int kk = kkh % 24, h = kkh / 24;
    const float* W = (nt < 4) ? Wk : Wv;
    int row = h * 64 + (nt & 3) * 16 + (ln & 15);
    int k0 = kk * 32 + (ln >> 4) * 8;
    bf16x8 v;
    #pragma unroll
    for (int j = 0; j < 8; j++) v[j] = (short)f2bf(W[(size_t)row * CD_ + k0 + j]);
    *(bf16x8*)&wkv_pk[(size_t)slot * 8] = v;
  }
}

// ---------------- A2: fused context pipeline: KV-proj (MFMA) + mask + softmax + attn (MFMA) ----------------
// one block per (b,h); 256 threads = 4 waves; wave w owns ctx rows [64w,64w+64)
__global__ __launch_bounds__(256) void ctx_attn(const unsigned short* __restrict__ ctx_nb,
    const unsigned short* __restrict__ wkv_pk,
    const float* __restrict__ bk, const float* __restrict__ bv,
    const int* __restrict__ mask, unsigned short* __restrict__ apk){
  __shared__ __align__(16) char smem[75776];
  unsigned short* a_st  = (unsigned short*)smem;            // [2][8192] staging (aliases p_lds)
  unsigned short* p_lds = (unsigned short*)smem;            // [64][256] bf16, d-major
  unsigned short* v_lds = (unsigned short*)(smem + 32768);  // [64][256] bf16, e-major
  unsigned short* al    = (unsigned short*)(smem + 65536);  // [64][64] attn bf16
  float* wred = (float*)(smem + 73728);                     // [4][64]
  int* msk_l  = (int*)(smem + 74752);                       // [256]

  const int tid = threadIdx.x;
  const int b = blockIdx.x >> 3, h = blockIdx.x & 7;
  msk_l[tid] = mask[b * 256 + tid];

  const unsigned short* cb = ctx_nb + (size_t)b * 256 * CD_;
  const int w = tid >> 6, ln = tid & 63, lc = ln & 15, lk = ln >> 4;

  // stage kk=0 (row = tid, 32 k-values = 4 x bf16x8)
  {
    const bf16x8* src = (const bf16x8*)(cb + (size_t)tid * CD_);
    #pragma unroll
    for (int s = 0; s < 4; s++){
      bf16x8 vv = src[s];
      *(bf16x8*)&a_st[(tid * 32 + s * 8) ^ ((tid & 7) << 3)] = vv;
    }
  }
  const bf16x8* wv_ = (const bf16x8*)wkv_pk;
  const size_t wbase = (size_t)h * 24 * 8 * 64;
  f32x4 acc[4][8];
  #pragma unroll
  for (int i = 0; i < 4; i++)
    #pragma unroll
    for (int j = 0; j < 8; j++) acc[i][j] = (f32x4){0.f,0.f,0.f,0.f};
  bf16x8 bbuf[2][8];
  #pragma unroll
  for (int nt = 0; nt < 8; nt++) bbuf[0][nt] = wv_[wbase + (size_t)(0 * 8 + nt) * 64 + ln];
  __syncthreads();

  // GEMM: M=256 (n), N=128 (64 k-d | 64 v-e), K=768; reg-staged prefetch (loads issued
  // before MFMAs so the vmcnt wait lands after them; LDS write deferred past compute)
  for (int kk = 0; kk < 24; kk++){
    int cur = kk & 1;
    bf16x8 nx[4];
    if (kk < 23){
      const bf16x8* src = (const bf16x8*)(cb + (size_t)tid * CD_ + (kk + 1) * 32);
      #pragma unroll
      for (int s = 0; s < 4; s++) nx[s] = src[s];
      #pragma unroll
      for (int nt = 0; nt < 8; nt++)
        bbuf[cur ^ 1][nt] = wv_[wbase + (size_t)((kk + 1) * 8 + nt) * 64 + ln];
    }
    bf16x8 af[4];
    #pragma unroll
    for (int mt = 0; mt < 4; mt++){
      int row = w * 64 + mt * 16 + lc;
      af[mt] = *(const bf16x8*)&a_st[cur * 8192 + ((row * 32 + lk * 8) ^ ((row & 7) << 3))];
    }
    #pragma unroll
    for (int mt = 0; mt < 4; mt++)
      #pragma unroll
      for (int nt = 0; nt < 8; nt++)
        acc[mt][nt] = __builtin_amdgcn_mfma_f32_16x16x32_bf16(af[mt], bbuf[cur][nt], acc[mt][nt], 0, 0, 0);
    if (kk < 23){
      unsigned short* dst = a_st + (cur ^ 1) * 8192;
      #pragma unroll
      for (int s = 0; s < 4; s++)
        *(bf16x8*)&dst[(tid * 32 + s * 8) ^ ((tid & 7) << 3)] = nx[s];
    }
    __syncthreads();
  }

  // bias + mask
  float bia[8];
  #pragma unroll
  for (int nt = 0; nt < 8; nt++)
    bia[nt] = (nt < 4) ? bk[h * 64 + nt * 16 + lc] : bv[h * 64 + (nt - 4) * 16 + lc];
  bool mk[4][4];
  #pragma unroll
  for (int mt = 0; mt < 4; mt++)
    #pragma unroll
    for (int r = 0; r < 4; r++)
      mk[mt][r] = msk_l[w * 64 + mt * 16 + lk * 4 + r] != 0;

  // softmax over n for k-part (nt 0..3): column d = nt*16+lc
  float cred[4];
  #pragma unroll
  for (int nt = 0; nt < 4; nt++){
    float mx = -3.402823466e38f;
    #pragma unroll
    for (int mt = 0; mt < 4; mt++)
      #pragma unroll
      for (int r = 0; r < 4; r++)
        if (mk[mt][r]) mx = fmaxf(mx, acc[mt][nt][r] + bia[nt]);
    mx = fmaxf(mx, __shfl_xor(mx, 16));
    mx = fmaxf(mx, __shfl_xor(mx, 32));
    cred[nt] = mx;
  }
  if (lk == 0){
    #pragma unroll
    for (int nt = 0; nt < 4; nt++) wred[w * 64 + nt * 16 + lc] = cred[nt];
  }
  __syncthreads();
  float gmx[4];
  #pragma unroll
  for (int nt = 0; nt < 4; nt++){
    int d = nt * 16 + lc;
    gmx[nt] = fmaxf(fmaxf(wred[d], wred[64 + d]), fmaxf(wred[128 + d], wred[192 + d]));
  }
  __syncthreads();
  #pragma unroll
  for (int nt = 0; nt < 4; nt++){
    float s = 0.f;
    #pragma unroll
    for (int mt = 0; mt < 4; mt++)
      #pragma unroll
      for (int r = 0; r < 4; r++){
        float p = mk[mt][r] ? expf(acc[mt][nt][r] + bia[nt] - gmx[nt]) : 0.f;
        acc[mt][nt][r] = p;
        s += p;
      }
    s += __shfl_xor(s, 16);
    s += __shfl_xor(s, 32);
    cred[nt] = s;
  }
  if (lk == 0){
    #pragma unroll
    for (int nt = 0; nt < 4; nt++) wred[w * 64 + nt * 16 + lc] = cred[nt];
  }
  __syncthreads();
  float ginv[4];
  #pragma unroll
  for (int nt = 0; nt < 4; nt++){
    int d = nt * 16 + lc;
    float s = wred[d] + wred[64 + d] + wred[128 + d] + wred[192 + d];
    ginv[nt] = 1.0f / fmaxf(s, 1e-30f);
  }
  // write p_lds[d][n], v_lds[e][n] (bf16, row-swizzled) — safe: all GEMM reads done
  #pragma unroll
  for (int nt = 0; nt < 4; nt++){
    int d = nt * 16 + lc;
    #pragma unroll
    for (int mt = 0; mt < 4; mt++)
      #pragma unroll
      for (int r = 0; r < 4; r++){
        int n = w * 64 + mt * 16 + lk * 4 + r;
        p_lds[(d * 256 + n) ^ ((d & 7) << 3)] = f2bf(acc[mt][nt][r] * ginv[nt]);
      }
  }
  #pragma unroll
  for (int nt = 4; nt < 8; nt++){
    int e = (nt - 4) * 16 + lc;
    #pragma unroll
    for (int mt = 0; mt < 4; mt++)
      #pragma unroll
      for (int r = 0; r < 4; r++){
        int n = w * 64 + mt * 16 + lk * 4 + r;
        float vv = mk[mt][r] ? (acc[mt][nt][r] + bia[nt]) : 0.f;
        v_lds[(e * 256 + n) ^ ((e & 7) << 3)] = f2bf(vv);
      }
  }
  __syncthreads();

  // attn = p^T @ v : M=64(d) N=64(e) K=256(n); wave w does d-rows [16w,16w+16)
  f32x4 acc2[4];
  #pragma unroll
  for (int i = 0; i < 4; i++) acc2[i] = (f32x4){0.f,0.f,0.f,0.f};
  #pragma unroll
  for (int kk = 0; kk < 8; kk++){
    int d = w * 16 + lc;
    bf16x8 pa = *(const bf16x8*)&p_lds[(d * 256 + kk * 32 + lk * 8) ^ ((d & 7) << 3)];
    #pragma unroll
    for (int nt2 = 0; nt2 < 4; nt2++){
      int e = nt2 * 16 + lc;
      bf16x8 vb = *(const bf16x8*)&v_lds[(e * 256 + kk * 32 + lk * 8) ^ ((e & 7) << 3)];
      acc2[nt2] = __builtin_amdgcn_mfma_f32_16x16x32_bf16(pa, vb, acc2[nt2], 0, 0, 0);
    }
  }
  #pragma unroll
  for (int nt2 = 0; nt2 < 4; nt2++)
    #pragma unroll
    for (int r = 0; r < 4; r++)
      al[(w * 16 + lk * 4 + r) * 64 + nt2 * 16 + lc] = f2bf(acc2[nt2][r]);
  __syncthreads();

  // pack apk: slot=(kk*4+nt)*64+l2 ; elem j = al[(kk*32+(l2>>4)*8+j)*64 + nt*16+(l2&15)]
  // (valid both as B-frag of attn and as A-frag of attn^T — A/B share the per-lane layout)
  #pragma unroll
  for (int s2 = 0; s2 < 2; s2++){
    int slot = s2 * 256 + tid;           // 0..511
    int l2 = slot & 63, nt = (slot >> 6) & 3, kk = slot >> 8;
    int e = nt * 16 + (l2 & 15), d0 = kk * 32 + (l2 >> 4) * 8;
    bf16x8 v;
    #pragma unroll
    for (int j = 0; j < 8; j++) v[j] = (short)al[(d0 + j) * 64 + e];
    *(bf16x8*)&apk[((size_t)(b * 8 + h) * 512 + slot) * 8] = v;
  }
}

// ---------------- B: fused LN -> Q-proj (MFMA) -> softmax -> PV^T (MFMA) -> residual ----------------
__global__ __launch_bounds__(256, 3) void fused_main(const float* __restrict__ x,
    const float* __restrict__ g, const float* __restrict__ bl,
    const unsigned short* __restrict__ wq_pk, const float* __restrict__ bq,
    const unsigned short* __restrict__ attn_pk, float* __restrict__ out){
  __shared__ unsigned short a_lds[32 * 512];   // bf16 A-tile (swizzled); reused for P
  __shared__ float red[32 * 8 * 2];
  __shared__ float m_l[32], rs_l[32];
  const int tid = threadIdx.x;
  const int b = blockIdx.y;
  const int t0 = blockIdx.x * 32;
  const float* xb = x + (size_t)b * C_ * T_ + t0;
  const int t = tid & 31, cg = tid >> 5;

  // pass 1: single global read; stats in f32; keep x as packed bf16 in registers
  unsigned int xr[32];
  {
    float s1 = 0.f, s2 = 0.f;
    #pragma unroll
    for (int jj = 0; jj < 32; jj++){
      float v0 = xb[(size_t)(cg * 64 + 2 * jj + 0) * T_ + t];
      float v1 = xb[(size_t)(cg * 64 + 2 * jj + 1) * T_ + t];
      s1 += v0 + v1; s2 += v0 * v0 + v1 * v1;
      xr[jj] = (unsigned)f2bf(v0) | ((unsigned)f2bf(v1) << 16);
    }
    red[(t * 8 + cg) * 2 + 0] = s1;
    red[(t * 8 + cg) * 2 + 1] = s2;
  }
  __syncthreads();
  if (tid < 32){
    float s1 = 0.f, s2 = 0.f;
    #pragma unroll
    for (int j = 0; j < 8; j++){ s1 += red[(tid*8+j)*2]; s2 += red[(tid*8+j)*2+1]; }
    float m = s1 * (1.0f / 512.0f);
    float var = s2 * (1.0f / 512.0f) - m * m;
    m_l[tid] = m;
    rs_l[tid] = rsqrtf(var + 1e-5f);
  }
  __syncthreads();
  // pass 2: LN from registers -> bf16 A tile (XOR-swizzled rows); no global re-read
  {
    float m = m_l[t], rs = rs_l[t];
    #pragma unroll
    for (int o = 0; o < 8; o++){
      int c0 = cg * 64 + o * 8;
      bf16x8 av;
      #pragma unroll
      for (int j = 0; j < 8; j++){
        unsigned u = xr[o * 4 + (j >> 1)];
        float v = bf2f((unsigned short)((j & 1) ? (u >> 16) : (u & 0xffffu)));
        int c = c0 + j;
        av[j] = (short)f2bf((v - m) * rs * g[c] + bl[c]);
      }
      *(bf16x8*)&a_lds[(t * 512 + c0) ^ ((t & 7) << 3)] = av;
    }
  }
  __syncthreads();

  const int w = tid >> 6, ln = tid & 63, lc = ln & 15, lk = ln >> 4;
  // ---- Q GEMM: M=32, per-wave N=128, K=512 ----
  f32x4 acc[2][8];
  #pragma unroll
  for (int i = 0; i < 2; i++)
    #pragma unroll
    for (int j = 0; j < 8; j++) acc[i][j] = (f32x4){0.f, 0.f, 0.f, 0.f};
  const bf16x8* wqv = (const bf16x8*)wq_pk;
  bf16x8 bbuf[2][8];
  #pragma unroll
  for (int nt = 0; nt < 8; nt++) bbuf[0][nt] = wqv[(size_t)(w * 8 + nt) * 64 + ln];
  #pragma unroll
  for (int kk = 0; kk < 16; kk++){
    int cur = kk & 1, nxt = cur ^ 1;
    if (kk < 15){
      #pragma unroll
      for (int nt = 0; nt < 8; nt++)
        bbuf[nxt][nt] = wqv[(size_t)((kk + 1) * 32 + w * 8 + nt) * 64 + ln];
    }
    bf16x8 af[2];
    #pragma unroll
    for (int mt = 0; mt < 2; mt++){
      int tr = mt * 16 + lc;
      af[mt] = *(const bf16x8*)&a_lds[(tr * 512 + kk * 32 + lk * 8) ^ ((tr & 7) << 3)];
    }
    #pragma unroll
    for (int mt = 0; mt < 2; mt++)
      #pragma unroll
      for (int nt = 0; nt < 8; nt++)
        acc[mt][nt] = __builtin_amdgcn_mfma_f32_16x16x32_bf16(af[mt], bbuf[cur][nt], acc[mt][nt], 0, 0, 0);
  }
  // attn fragments (A-operand of attn^T in the PV^T step)
  bf16x8 b2[2][2][4];
  const bf16x8* apk = (const bf16x8*)attn_pk;
  #pragma unroll
  for (int hh = 0; hh < 2; hh++)
    #pragma unroll
    for (int k2 = 0; k2 < 2; k2++)
      #pragma unroll
      for (int np = 0; np < 4; np++)
        b2[hh][k2][np] = apk[((size_t)(b * 8 + (2 * w + hh)) * 512 + (k2 * 4 + np) * 64 + ln)];
  // bias + per-head softmax over D=64
  float bqv[8];
  #pragma unroll
  for (int nt = 0; nt < 8; nt++) bqv[nt] = bq[w * 128 + nt * 16 + lc];
  #pragma unroll
  for (int mt = 0; mt < 2; mt++)
    #pragma unroll
    for (int r = 0; r < 4; r++)
      #pragma unroll
      for (int h2 = 0; h2 < 2; h2++){
        float v[4];
        #pragma unroll
        for (int j = 0; j < 4; j++) v[j] = acc[mt][h2 * 4 + j][r] + bqv[h2 * 4 + j];
        float mx = fmaxf(fmaxf(v[0], v[1]), fmaxf(v[2], v[3]));
        #pragma unroll
        for (int o = 1; o < 16; o <<= 1) mx = fmaxf(mx, __shfl_xor(mx, o));
        float e[4], s = 0.f;
        #pragma unroll
        for (int j = 0; j < 4; j++){ e[j] = expf(v[j] - mx); s += e[j]; }
        #pragma unroll
        for (int o = 1; o < 16; o <<= 1) s += __shfl_xor(s, o);
        float inv = 1.0f / s;
        #pragma unroll
        for (int j = 0; j < 4; j++) acc[mt][h2 * 4 + j][r] = e[j] * inv;
      }
  __syncthreads();                 // A-tile reads complete
  // store P (bf16) into a_lds (same swizzle): P[t][n], n = w*128 + nt*16 + lc
  #pragma unroll
  for (int mt = 0; mt < 2; mt++)
    #pragma unroll
    for (int r = 0; r < 4; r++){
      int tr = mt * 16 + lk * 4 + r;
      #pragma unroll
      for (int nt = 0; nt < 8; nt++){
        int col = w * 128 + nt * 16 + lc;
        a_lds[(tr * 512 + col) ^ ((tr & 7) << 3)] = f2bf(acc[mt][nt][r]);
      }
    }
  __syncthreads();
  // ---- PV^T: o^T[c][t] = attn^T (A=b2) @ P^T (B=pb). D: row=c_local, col=t_local ----
  f32x4 acc2[2][4][2];             // [hh][mtc(c)][ntt(t)]
  #pragma unroll
  for (int i = 0; i < 2; i++)
    #pragma unroll
    for (int j = 0; j < 4; j++)
      #pragma unroll
      for (int k = 0; k < 2; k++) acc2[i][j][k] = (f32x4){0.f, 0.f, 0.f, 0.f};
  #pragma unroll
  for (int k2 = 0; k2 < 2; k2++){
    bf16x8 pb[2][2];
    #pragma unroll
    for (int hh = 0; hh < 2; hh++)
      #pragma unroll
      for (int ntt = 0; ntt < 2; ntt++){
        int tr = ntt * 16 + lc;
        int col = w * 128 + hh * 64 + k2 * 32 + lk * 8;
        pb[hh][ntt] = *(const bf16x8*)&a_lds[(tr * 512 + col) ^ ((tr & 7) << 3)];
      }
    #pragma unroll
    for (int hh = 0; hh < 2; hh++)
      #pragma unroll
      for (int mtc = 0; mtc < 4; mtc++)
        #pragma unroll
        for (int ntt = 0; ntt < 2; ntt++)
          acc2[hh][mtc][ntt] = __builtin_amdgcn_mfma_f32_16x16x32_bf16(b2[hh][k2][mtc], pb[hh][ntt], acc2[hh][mtc][ntt], 0, 0, 0);
  }
  // ---- epilogue: direct coalesced stores (64B segments), residual from global ----
  #pragma unroll
  for (int hh = 0; hh < 2; hh++)
    #pragma unroll
    for (int mtc = 0; mtc < 4; mtc++)
      #pragma unroll
      for (int ntt = 0; ntt < 2; ntt++)
        #pragma unroll
        for (int r = 0; r < 4; r++){
          int c = w * 128 + hh * 64 + mtc * 16 + lk * 4 + r;
          int tt2 = ntt * 16 + lc;
          float xv = xb[(size_t)c * T_ + tt2];
          out[((size_t)b * C_ + c) * T_ + t0 + tt2] = xv + acc2[hh][mtc][ntt][r];
        }
}

extern "C" void kernel_launch(void* const* d_in, const int* in_sizes, int n_in,
                              void* d_out, int out_size, void* d_ws, size_t ws_size,
                              hipStream_t stream) {
  (void)in_sizes; (void)n_in; (void)out_size; (void)ws_size;
  const float* x     = (const float*)d_in[0];
  const float* ctx   = (const float*)d_in[1];
  const int*   mask  = (const int*)d_in[2];
  const float* ln_g  = (const float*)d_in[3];
  const float* ln_b  = (const float*)d_in[4];
  const float* cln_g = (const float*)d_in[5];
  const float* cln_b = (const float*)d_in[6];
  const float* Wq    = (const float*)d_in[7];
  const float* bq    = (const float*)d_in[8];
  const float* Wk    = (const float*)d_in[9];
  const float* bk    = (const float*)d_in[10];
  const float* Wv    = (const float*)d_in[11];
  const float* bv    = (const float*)d_in[12];
  float* out = (float*)d_out;
  char* wsb = (char*)d_ws;
  unsigned short* ctx_nb = (unsigned short*)wsb;                // 3,145,728 B
  unsigned short* wq_pk  = (unsigned short*)(wsb + 3145728);    //   524,288 B
  unsigned short* wkv_pk = (unsigned short*)(wsb + 3670016);    // 1,572,864 B
  unsigned short* apk    = (unsigned short*)(wsb + 5242880);    //   524,288 B

  prep<<<2560, 256, 0, stream>>>(ctx, cln_g, cln_b, Wq, Wk, Wv, ctx_nb, wq_pk, wkv_pk);
  ctx_attn<<<64, 256, 0, stream>>>(ctx_nb, wkv_pk, bk, bv, mask, apk);
  fused_main<<<dim3(T_ / 32, B_), 256, 0, stream>>>(x, ln_g, ln_b, wq_pk, bq, apk, out);
}